// Round 1
// baseline (664.686 us; speedup 1.0000x reference)
//
#include <hip/hip_runtime.h>

#define DIMD 512
#define BT 128
#define KC 16
#define LDT 132   // padded row stride (floats): 132*4=528B, 16B-aligned, spreads banks

// ws layout (bytes):
//   0      : sq[8192]  f32   (32768 B)
//   32768  : colsum[512] f64 (4096 B)
//   36864  : sumsq f64
//   36872  : acc   f64
//   36880  : gamma f32

__global__ __launch_bounds__(256) void rowsq_kernel(const float* __restrict__ src,
                                                    const float* __restrict__ tgt,
                                                    float* __restrict__ sq,
                                                    double* __restrict__ sumsq,
                                                    int b, int n) {
    int wave = threadIdx.x >> 6;
    int lane = threadIdx.x & 63;
    int row = blockIdx.x * 4 + wave;
    if (row >= n) return;
    const float* p = (row < b) ? (src + (size_t)row * DIMD)
                               : (tgt + (size_t)(row - b) * DIMD);
    float4 v0 = *(const float4*)(p + lane * 8);
    float4 v1 = *(const float4*)(p + lane * 8 + 4);
    float s = v0.x*v0.x + v0.y*v0.y + v0.z*v0.z + v0.w*v0.w
            + v1.x*v1.x + v1.y*v1.y + v1.z*v1.z + v1.w*v1.w;
    #pragma unroll
    for (int off = 32; off; off >>= 1) s += __shfl_down(s, off);
    if (lane == 0) {
        sq[row] = s;
        atomicAdd(sumsq, (double)s);
    }
}

__global__ __launch_bounds__(512) void colsum_kernel(const float* __restrict__ src,
                                                     const float* __restrict__ tgt,
                                                     double* __restrict__ colsum,
                                                     int b, int rowsPerBlock) {
    int col = threadIdx.x;             // 512 threads = 512 columns
    int r0 = blockIdx.x * rowsPerBlock;
    double s = 0.0;
    for (int i = 0; i < rowsPerBlock; ++i) {
        int row = r0 + i;
        const float* p = (row < b) ? (src + (size_t)row * DIMD)
                                   : (tgt + (size_t)(row - b) * DIMD);
        s += (double)p[col];
    }
    atomicAdd(&colsum[col], s);
}

__global__ __launch_bounds__(256) void bw_kernel(const double* __restrict__ colsum,
                                                 const double* __restrict__ sumsq,
                                                 float* __restrict__ gamma,
                                                 int n) {
    __shared__ double red[256];
    double s = 0.0;
    for (int c = threadIdx.x; c < DIMD; c += 256) {
        double v = colsum[c];
        s += v * v;
    }
    red[threadIdx.x] = s;
    __syncthreads();
    for (int off = 128; off; off >>= 1) {
        if (threadIdx.x < off) red[threadIdx.x] += red[threadIdx.x + off];
        __syncthreads();
    }
    if (threadIdx.x == 0) {
        double sum_l2 = 2.0 * (double)n * sumsq[0] - 2.0 * red[0];
        double nn = (double)n * (double)n - (double)n;
        double bw = sum_l2 / nn / 4.0;    // KERNEL_MUL^(KERNEL_NUM//2) = 2^2
        gamma[0] = (float)(1.0 / (16.0 * bw));
    }
}

__global__ __launch_bounds__(256) void pair_kernel(const float* __restrict__ src,
                                                   const float* __restrict__ tgt,
                                                   const float* __restrict__ sq,
                                                   const float* __restrict__ gamma_p,
                                                   double* __restrict__ acc_out,
                                                   int b) {
    int ti = blockIdx.x, tj = blockIdx.y;
    if (tj < ti) return;                  // symmetric: upper triangle only
    int rowBase = ti * BT, colBase = tj * BT;

    const float* Abase = (rowBase < b) ? (src + (size_t)rowBase * DIMD)
                                       : (tgt + (size_t)(rowBase - b) * DIMD);
    const float* Bbase = (colBase < b) ? (src + (size_t)colBase * DIMD)
                                       : (tgt + (size_t)(colBase - b) * DIMD);

    __shared__ float As[KC][LDT];
    __shared__ float Bs[KC][LDT];

    float acc[8][8];
    #pragma unroll
    for (int r = 0; r < 8; ++r)
        #pragma unroll
        for (int c = 0; c < 8; ++c) acc[r][c] = 0.f;

    int t = threadIdx.x;
    int tx = t & 15, ty = t >> 4;
    int lrow = t >> 2;          // 0..63
    int lk = (t & 3) * 4;       // 0,4,8,12

    for (int k0 = 0; k0 < DIMD; k0 += KC) {
        #pragma unroll
        for (int h = 0; h < 2; ++h) {
            int r = lrow + h * 64;
            float4 a  = *(const float4*)(Abase + (size_t)r * DIMD + k0 + lk);
            float4 bv = *(const float4*)(Bbase + (size_t)r * DIMD + k0 + lk);
            As[lk + 0][r] = a.x;  As[lk + 1][r] = a.y;
            As[lk + 2][r] = a.z;  As[lk + 3][r] = a.w;
            Bs[lk + 0][r] = bv.x; Bs[lk + 1][r] = bv.y;
            Bs[lk + 2][r] = bv.z; Bs[lk + 3][r] = bv.w;
        }
        __syncthreads();
        #pragma unroll
        for (int kk = 0; kk < KC; ++kk) {
            float4 a0 = *(const float4*)&As[kk][ty * 4];
            float4 a1 = *(const float4*)&As[kk][64 + ty * 4];
            float4 b0 = *(const float4*)&Bs[kk][tx * 4];
            float4 b1 = *(const float4*)&Bs[kk][64 + tx * 4];
            float av[8] = {a0.x, a0.y, a0.z, a0.w, a1.x, a1.y, a1.z, a1.w};
            float bv[8] = {b0.x, b0.y, b0.z, b0.w, b1.x, b1.y, b1.z, b1.w};
            #pragma unroll
            for (int r = 0; r < 8; ++r)
                #pragma unroll
                for (int c = 0; c < 8; ++c)
                    acc[r][c] = fmaf(av[r], bv[c], acc[r][c]);
        }
        __syncthreads();
    }

    // fused epilogue: l2 -> 5-scale kernel sum via t + t^2 + t^4 + t^8 + t^16
    float gamma = gamma_p[0];
    float rowsq[8], colsq[8];
    #pragma unroll
    for (int r = 0; r < 8; ++r) {
        int lr = (r < 4) ? (ty * 4 + r) : (64 + ty * 4 + r - 4);
        rowsq[r] = sq[rowBase + lr];
    }
    #pragma unroll
    for (int c = 0; c < 8; ++c) {
        int lc = (c < 4) ? (tx * 4 + c) : (64 + tx * 4 + c - 4);
        colsq[c] = sq[colBase + lc];
    }

    float psum = 0.f;
    #pragma unroll
    for (int r = 0; r < 8; ++r)
        #pragma unroll
        for (int c = 0; c < 8; ++c) {
            float l2 = rowsq[r] + colsq[c] - 2.f * acc[r][c];
            l2 = fmaxf(l2, 0.f);
            float t1 = __expf(-l2 * gamma);     // exp(-l2/(16 bw))
            float t2 = t1 * t1;
            float t4 = t2 * t2;
            float t8 = t4 * t4;
            float t16 = t8 * t8;
            psum += t1 + t2 + t4 + t8 + t16;
        }

    float w = ((ti == tj) ? 1.f : 2.f)
            * ((rowBase < b) ? 1.f : -1.f)
            * ((colBase < b) ? 1.f : -1.f);
    double v = (double)psum * (double)w;
    #pragma unroll
    for (int off = 32; off; off >>= 1) v += __shfl_down(v, off);

    __shared__ double wred[4];
    if ((t & 63) == 0) wred[t >> 6] = v;
    __syncthreads();
    if (t == 0) atomicAdd(acc_out, wred[0] + wred[1] + wred[2] + wred[3]);
}

__global__ void out_kernel(const double* __restrict__ acc,
                           float* __restrict__ out, int b) {
    double bb = (double)b * (double)b;
    out[0] = (float)(acc[0] / bb);
}

extern "C" void kernel_launch(void* const* d_in, const int* in_sizes, int n_in,
                              void* d_out, int out_size, void* d_ws, size_t ws_size,
                              hipStream_t stream) {
    const float* src = (const float*)d_in[0];
    const float* tgt = (const float*)d_in[1];
    int b = in_sizes[0] / DIMD;   // 4096
    int n = 2 * b;                // 8192

    char* ws = (char*)d_ws;
    float*  sq     = (float*)ws;
    double* colsum = (double*)(ws + 32768);
    double* sumsq  = (double*)(ws + 36864);
    double* acc    = (double*)(ws + 36872);
    float*  gamma  = (float*)(ws + 36880);

    // zero the accumulators (ws is poisoned 0xAA before every timed call)
    hipMemsetAsync(ws + 32768, 0, 4096 + 16, stream);

    rowsq_kernel<<<n / 4, 256, 0, stream>>>(src, tgt, sq, sumsq, b, n);
    colsum_kernel<<<64, 512, 0, stream>>>(src, tgt, colsum, b, n / 64);
    bw_kernel<<<1, 256, 0, stream>>>(colsum, sumsq, gamma, n);

    int nt = n / BT;              // 64
    dim3 grid(nt, nt);
    pair_kernel<<<grid, 256, 0, stream>>>(src, tgt, sq, gamma, acc, b);

    out_kernel<<<1, 1, 0, stream>>>(acc, (float*)d_out, b);
}

// Round 2
// 316.144 us; speedup vs baseline: 2.1025x; 2.1025x over previous
//
#include <hip/hip_runtime.h>

typedef unsigned short u16;
typedef __attribute__((ext_vector_type(8))) short short8;
typedef __attribute__((ext_vector_type(8))) unsigned short ushort8;
typedef __attribute__((ext_vector_type(4))) float f32x4;

#define DIMD 512
#define BTILE 128
#define KC 32
#define NTILE 64      // 8192 / 128
#define NPAIRS 2080   // NTILE*(NTILE+1)/2

// ws layout (bytes)
#define WS_AH 0ull
#define WS_AL (8192ull * 512 * 2)                 // 8388608
#define WS_SQ (2ull * 8192 * 512 * 2)             // 16777216, f32[8192]
#define WS_COLSUM (WS_SQ + 32768)                 // f64[512]
#define WS_SUMSQ (WS_COLSUM + 4096)
#define WS_ACC (WS_SUMSQ + 8)
#define WS_GAMMA (WS_ACC + 8)

__device__ __forceinline__ u16 f2bf(float f) {
    union { float f; unsigned u; } c; c.f = f;
    unsigned u = c.u;
    unsigned r = u + 0x7FFFu + ((u >> 16) & 1u);
    return (u16)(r >> 16);
}
__device__ __forceinline__ float bf2f(u16 h) {
    union { unsigned u; float f; } c; c.u = ((unsigned)h) << 16;
    return c.f;
}

typedef const unsigned int __attribute__((address_space(1)))* gas1_t;
typedef unsigned int __attribute__((address_space(3)))* las3_t;
__device__ __forceinline__ void ld_g2l_16(const void* g, void* l) {
    __builtin_amdgcn_global_load_lds((gas1_t)(unsigned long long)g,
                                     (las3_t)(unsigned int)(unsigned long long)l,
                                     16, 0, 0);
}

// ---- prep: f32 -> (hi, lo) bf16 split + row sumsq + total sumsq ----
__global__ __launch_bounds__(256) void prep_kernel(const float* __restrict__ src,
                                                   const float* __restrict__ tgt,
                                                   u16* __restrict__ Ah, u16* __restrict__ Al,
                                                   float* __restrict__ sq,
                                                   double* __restrict__ sumsq,
                                                   int b, int n) {
    int wave = threadIdx.x >> 6, lane = threadIdx.x & 63;
    int row = blockIdx.x * 4 + wave;
    if (row >= n) return;
    const float* p = (row < b) ? (src + (size_t)row * DIMD)
                               : (tgt + (size_t)(row - b) * DIMD);
    float4 v0 = *(const float4*)(p + lane * 8);
    float4 v1 = *(const float4*)(p + lane * 8 + 4);
    float x[8] = {v0.x, v0.y, v0.z, v0.w, v1.x, v1.y, v1.z, v1.w};
    ushort8 hi, lo;
    float s = 0.f;
    #pragma unroll
    for (int i = 0; i < 8; ++i) {
        s = fmaf(x[i], x[i], s);
        u16 h = f2bf(x[i]);
        hi[i] = h;
        lo[i] = f2bf(x[i] - bf2f(h));
    }
    *(ushort8*)(Ah + (size_t)row * DIMD + lane * 8) = hi;
    *(ushort8*)(Al + (size_t)row * DIMD + lane * 8) = lo;
    #pragma unroll
    for (int off = 32; off; off >>= 1) s += __shfl_down(s, off);
    if (lane == 0) {
        sq[row] = s;
        atomicAdd(sumsq, (double)s);
    }
}

// ---- column sums (for ||sum x||^2 term of the bandwidth) ----
__global__ __launch_bounds__(512) void colsum_kernel(const float* __restrict__ src,
                                                     const float* __restrict__ tgt,
                                                     double* __restrict__ colsum,
                                                     int b, int rowsPerBlock) {
    int col = threadIdx.x;
    int r0 = blockIdx.x * rowsPerBlock;
    double s = 0.0;
    for (int i = 0; i < rowsPerBlock; ++i) {
        int row = r0 + i;
        const float* p = (row < b) ? (src + (size_t)row * DIMD)
                                   : (tgt + (size_t)(row - b) * DIMD);
        s += (double)p[col];
    }
    atomicAdd(&colsum[col], s);
}

__global__ __launch_bounds__(256) void bw_kernel(const double* __restrict__ colsum,
                                                 const double* __restrict__ sumsq,
                                                 float* __restrict__ gamma,
                                                 int n) {
    __shared__ double red[256];
    double s = 0.0;
    for (int c = threadIdx.x; c < DIMD; c += 256) {
        double v = colsum[c];
        s += v * v;
    }
    red[threadIdx.x] = s;
    __syncthreads();
    for (int off = 128; off; off >>= 1) {
        if (threadIdx.x < off) red[threadIdx.x] += red[threadIdx.x + off];
        __syncthreads();
    }
    if (threadIdx.x == 0) {
        double sum_l2 = 2.0 * (double)n * sumsq[0] - 2.0 * red[0];
        double nn = (double)n * (double)n - (double)n;
        double bw = sum_l2 / nn / 4.0;      // / KERNEL_MUL^(KERNEL_NUM//2)
        gamma[0] = (float)(1.0 / (16.0 * bw));
    }
}

// ---- MFMA pair kernel: 128x128 tile, BK=32, 2-way bf16 split (3 products) ----
__global__ __launch_bounds__(256) void pair_kernel(const u16* __restrict__ Ah,
                                                   const u16* __restrict__ Al,
                                                   const float* __restrict__ sq,
                                                   const float* __restrict__ gamma_p,
                                                   double* __restrict__ acc_out,
                                                   int b) {
    // triangular decode: block u -> (ti, tj), ti <= tj
    int u = blockIdx.x;
    int ti = (int)((2.f * NTILE + 1.f
                    - sqrtf((2.f * NTILE + 1.f) * (2.f * NTILE + 1.f) - 8.f * (float)u)) * 0.5f);
    while ((ti + 1) * NTILE - ((ti + 1) * ti) / 2 <= u) ++ti;
    while (ti * NTILE - (ti * (ti - 1)) / 2 > u) --ti;
    int tj = ti + (u - (ti * NTILE - (ti * (ti - 1)) / 2));
    int rowBase = ti * BTILE, colBase = tj * BTILE;

    // LDS: [0]=A_hi [1]=A_lo [2]=B_hi [3]=B_lo, each [128][32] bf16 (8 KB)
    __shared__ __align__(16) u16 lds[4][BTILE][KC];

    int t = threadIdx.x;
    int w = t >> 6, l = t & 63;
    int wr = w >> 1, wc = w & 1;           // wave -> 64x64 quadrant

    f32x4 acc[4][4];
    #pragma unroll
    for (int m = 0; m < 4; ++m)
        #pragma unroll
        for (int n = 0; n < 4; ++n) acc[m][n] = (f32x4){0.f, 0.f, 0.f, 0.f};

    const u16* gsrc[4];
    gsrc[0] = Ah + (size_t)rowBase * DIMD;
    gsrc[1] = Al + (size_t)rowBase * DIMD;
    gsrc[2] = Ah + (size_t)colBase * DIMD;
    gsrc[3] = Al + (size_t)colBase * DIMD;

    for (int k0 = 0; k0 < DIMD; k0 += KC) {
        // stage: each wave covers rows [w*32, w*32+32) of each of the 4 matrices.
        // LDS dest is linear (lane*16); source k-slot is pre-swizzled so that a
        // matching XOR on the read side is bank-conflict-free (rule #21).
        #pragma unroll
        for (int mat = 0; mat < 4; ++mat)
            #pragma unroll
            for (int h = 0; h < 2; ++h) {
                int r0 = w * 32 + h * 16;
                int row = r0 + (l >> 2);
                int slog = (l & 3) ^ ((row >> 1) & 3);
                const u16* g = gsrc[mat] + (size_t)row * DIMD + k0 + slog * 8;
                void* d = (char*)(&lds[0][0][0]) + mat * 8192 + r0 * 64;
                ld_g2l_16(g, d);
            }
        __syncthreads();   // compiler drains vmcnt(0) before s_barrier

        short8 af[2][4], bf[2][4];
        #pragma unroll
        for (int s = 0; s < 2; ++s)
            #pragma unroll
            for (int m = 0; m < 4; ++m) {
                int rowa = wr * 64 + m * 16 + (l & 15);
                int pa = (l >> 4) ^ ((rowa >> 1) & 3);
                af[s][m] = *(const short8*)((const char*)lds + s * 8192 + rowa * 64 + pa * 16);
                int rowb = wc * 64 + m * 16 + (l & 15);
                int pb = (l >> 4) ^ ((rowb >> 1) & 3);
                bf[s][m] = *(const short8*)((const char*)lds + (2 + s) * 8192 + rowb * 64 + pb * 16);
            }

        #pragma unroll
        for (int m = 0; m < 4; ++m)
            #pragma unroll
            for (int n = 0; n < 4; ++n) {
                acc[m][n] = __builtin_amdgcn_mfma_f32_16x16x32_bf16(af[0][m], bf[0][n], acc[m][n], 0, 0, 0);
                acc[m][n] = __builtin_amdgcn_mfma_f32_16x16x32_bf16(af[0][m], bf[1][n], acc[m][n], 0, 0, 0);
                acc[m][n] = __builtin_amdgcn_mfma_f32_16x16x32_bf16(af[1][m], bf[0][n], acc[m][n], 0, 0, 0);
            }
        __syncthreads();
    }

    // fused epilogue: l2 -> sum_k exp(-l2/scale_k) = t + t^2 + t^4 + t^8 + t^16
    float gamma = gamma_p[0];
    float sgn_r = (rowBase < b) ? 1.f : -1.f;
    float sgn_c = (colBase < b) ? 1.f : -1.f;
    float wgt = ((ti == tj) ? 1.f : 2.f) * sgn_r * sgn_c;

    float cs[4];
    #pragma unroll
    for (int n = 0; n < 4; ++n) cs[n] = sq[colBase + wc * 64 + n * 16 + (l & 15)];

    float psum = 0.f;
    #pragma unroll
    for (int m = 0; m < 4; ++m) {
        float rs[4];
        #pragma unroll
        for (int r = 0; r < 4; ++r)
            rs[r] = sq[rowBase + wr * 64 + m * 16 + (l >> 4) * 4 + r];
        #pragma unroll
        for (int n = 0; n < 4; ++n) {
            #pragma unroll
            for (int r = 0; r < 4; ++r) {
                float l2v = fmaxf(rs[r] + cs[n] - 2.f * acc[m][n][r], 0.f);
                float t1 = __expf(-l2v * gamma);
                float t2 = t1 * t1;
                float t4 = t2 * t2;
                float t8 = t4 * t4;
                float t16 = t8 * t8;
                psum += t1 + t2 + t4 + t8 + t16;
            }
        }
    }

    double v = (double)psum * (double)wgt;
    #pragma unroll
    for (int off = 32; off; off >>= 1) v += __shfl_down(v, off);
    __shared__ double wred[4];
    if (l == 0) wred[w] = v;
    __syncthreads();
    if (t == 0) atomicAdd(acc_out, wred[0] + wred[1] + wred[2] + wred[3]);
}

__global__ void out_kernel(const double* __restrict__ acc,
                           float* __restrict__ out, int b) {
    double bb = (double)b * (double)b;
    out[0] = (float)(acc[0] / bb);
}

extern "C" void kernel_launch(void* const* d_in, const int* in_sizes, int n_in,
                              void* d_out, int out_size, void* d_ws, size_t ws_size,
                              hipStream_t stream) {
    const float* src = (const float*)d_in[0];
    const float* tgt = (const float*)d_in[1];
    int b = in_sizes[0] / DIMD;   // 4096
    int n = 2 * b;                // 8192

    char* ws = (char*)d_ws;
    u16*    AhBuf  = (u16*)(ws + WS_AH);
    u16*    AlBuf  = (u16*)(ws + WS_AL);
    float*  sqBuf  = (float*)(ws + WS_SQ);
    double* colsum = (double*)(ws + WS_COLSUM);
    double* sumsq  = (double*)(ws + WS_SUMSQ);
    double* accum  = (double*)(ws + WS_ACC);
    float*  gamma  = (float*)(ws + WS_GAMMA);

    hipMemsetAsync(ws + WS_COLSUM, 0, 4096 + 16, stream);

    prep_kernel<<<n / 4, 256, 0, stream>>>(src, tgt, AhBuf, AlBuf, sqBuf, sumsq, b, n);
    colsum_kernel<<<128, 512, 0, stream>>>(src, tgt, colsum, b, n / 128);
    bw_kernel<<<1, 256, 0, stream>>>(colsum, sumsq, gamma, n);
    pair_kernel<<<NPAIRS, 256, 0, stream>>>(AhBuf, AlBuf, sqBuf, gamma, accum, b);
    out_kernel<<<1, 1, 0, stream>>>(accum, (float*)d_out, b);
}

// Round 3
// 135.480 us; speedup vs baseline: 4.9062x; 2.3335x over previous
//
#include <hip/hip_runtime.h>

typedef unsigned short u16;
typedef __attribute__((ext_vector_type(8))) short short8;
typedef __attribute__((ext_vector_type(8))) unsigned short ushort8;
typedef __attribute__((ext_vector_type(4))) float f32x4;

#define DIMD 512
#define BTILE 128
#define KC 32
#define NTILE 64      // 8192 / 128
#define NPAIRS 2080   // NTILE*(NTILE+1)/2
#define NSLOTS 64

// ws layout (bytes)
#define WS_H      0ull
#define WS_SQ     (8192ull * 512 * 2)            // f32 sq[8192]
#define WS_RED    (WS_SQ + 32768)                // start of small reduction area
// inside RED: colsum f32[512] @0, sumsq f64 @2048, slots f64[64] @2056, gamma f32 @2568
#define RED_BYTES 2576

__device__ __forceinline__ u16 f2bf(float f) {
    union { float f; unsigned u; } c; c.f = f;
    unsigned u = c.u;
    unsigned r = u + 0x7FFFu + ((u >> 16) & 1u);
    return (u16)(r >> 16);
}
__device__ __forceinline__ float bf2f(u16 h) {
    union { unsigned u; float f; } c; c.u = ((unsigned)h) << 16;
    return c.f;
}

typedef const unsigned int __attribute__((address_space(1)))* gas1_t;
typedef unsigned int __attribute__((address_space(3)))* las3_t;
__device__ __forceinline__ void ld_g2l_16(const void* g, void* l) {
    __builtin_amdgcn_global_load_lds((gas1_t)(unsigned long long)g,
                                     (las3_t)(unsigned int)(unsigned long long)l,
                                     16, 0, 0);
}

// ---- prep: f32 -> bf16 round; sq/colsum/sumsq all from the ROUNDED data ----
// 128 blocks x 256 threads, 64 rows per block (wave w: rows base+w*16 .. +15)
__global__ __launch_bounds__(256) void prep_kernel(const float* __restrict__ src,
                                                   const float* __restrict__ tgt,
                                                   u16* __restrict__ H,
                                                   float* __restrict__ sq,
                                                   float* __restrict__ colsum,
                                                   double* __restrict__ sumsq,
                                                   int b) {
    __shared__ float colred[DIMD];
    __shared__ double wsum[4];
    int t = threadIdx.x, w = t >> 6, l = t & 63;
    colred[t] = 0.f; colred[t + 256] = 0.f;
    __syncthreads();

    int base = blockIdx.x * 64 + w * 16;
    float colpart[8];
    #pragma unroll
    for (int i = 0; i < 8; ++i) colpart[i] = 0.f;
    double ssum = 0.0;

    for (int r = 0; r < 16; ++r) {
        int row = base + r;
        const float* p = (row < b) ? (src + (size_t)row * DIMD)
                                   : (tgt + (size_t)(row - b) * DIMD);
        float4 v0 = *(const float4*)(p + l * 8);
        float4 v1 = *(const float4*)(p + l * 8 + 4);
        float x[8] = {v0.x, v0.y, v0.z, v0.w, v1.x, v1.y, v1.z, v1.w};
        ushort8 hi;
        float s = 0.f;
        #pragma unroll
        for (int i = 0; i < 8; ++i) {
            u16 h = f2bf(x[i]);
            hi[i] = h;
            float xh = bf2f(h);
            s = fmaf(xh, xh, s);
            colpart[i] += xh;
        }
        *(ushort8*)(H + (size_t)row * DIMD + l * 8) = hi;
        #pragma unroll
        for (int off = 32; off; off >>= 1) s += __shfl_down(s, off);
        if (l == 0) { sq[row] = s; ssum += (double)s; }
    }

    #pragma unroll
    for (int i = 0; i < 8; ++i) atomicAdd(&colred[l * 8 + i], colpart[i]);
    if (l == 0) wsum[w] = ssum;
    __syncthreads();
    atomicAdd(&colsum[t], colred[t]);
    atomicAdd(&colsum[t + 256], colred[t + 256]);
    if (t == 0) atomicAdd(sumsq, wsum[0] + wsum[1] + wsum[2] + wsum[3]);
}

// ---- bandwidth -> gamma = 1/(16*bw) ----
__global__ __launch_bounds__(256) void bw_kernel(const float* __restrict__ colsum,
                                                 const double* __restrict__ sumsq,
                                                 float* __restrict__ gamma, int n) {
    __shared__ double red[256];
    double s = 0.0;
    for (int c = threadIdx.x; c < DIMD; c += 256) {
        double v = (double)colsum[c];
        s += v * v;
    }
    red[threadIdx.x] = s;
    __syncthreads();
    for (int off = 128; off; off >>= 1) {
        if (threadIdx.x < off) red[threadIdx.x] += red[threadIdx.x + off];
        __syncthreads();
    }
    if (threadIdx.x == 0) {
        double sum_l2 = 2.0 * (double)n * sumsq[0] - 2.0 * red[0];
        double nn = (double)n * (double)n - (double)n;
        double bw = sum_l2 / nn / 4.0;      // / KERNEL_MUL^(KERNEL_NUM//2)
        gamma[0] = (float)(1.0 / (16.0 * bw));
    }
}

// ---- MFMA pair kernel: 128x128 tile, BK=32, single bf16 Gram product ----
__global__ __launch_bounds__(256) void pair_kernel(const u16* __restrict__ H,
                                                   const float* __restrict__ sq,
                                                   const float* __restrict__ gamma_p,
                                                   double* __restrict__ slots,
                                                   int b) {
    // triangular decode: block u -> (ti, tj), ti <= tj
    int u = blockIdx.x;
    int ti = (int)((2.f * NTILE + 1.f
                    - sqrtf((2.f * NTILE + 1.f) * (2.f * NTILE + 1.f) - 8.f * (float)u)) * 0.5f);
    while ((ti + 1) * NTILE - ((ti + 1) * ti) / 2 <= u) ++ti;
    while (ti * NTILE - (ti * (ti - 1)) / 2 > u) --ti;
    int tj = ti + (u - (ti * NTILE - (ti * (ti - 1)) / 2));
    int rowBase = ti * BTILE, colBase = tj * BTILE;

    // LDS: [0]=A [1]=B, each [128][32] bf16 (8 KB), k-slots XOR-swizzled
    __shared__ __align__(16) u16 lds[2][BTILE][KC];

    int t = threadIdx.x;
    int w = t >> 6, l = t & 63;
    int wr = w >> 1, wc = w & 1;           // wave -> 64x64 quadrant

    f32x4 acc[4][4];
    #pragma unroll
    for (int m = 0; m < 4; ++m)
        #pragma unroll
        for (int n = 0; n < 4; ++n) acc[m][n] = (f32x4){0.f, 0.f, 0.f, 0.f};

    const u16* gsrc[2];
    gsrc[0] = H + (size_t)rowBase * DIMD;
    gsrc[1] = H + (size_t)colBase * DIMD;

    for (int k0 = 0; k0 < DIMD; k0 += KC) {
        // stage: wave w covers rows [w*32, w*32+32) of each matrix; LDS dest is
        // linear, global k-slot pre-swizzled to match the read-side XOR (rule #21)
        #pragma unroll
        for (int mat = 0; mat < 2; ++mat)
            #pragma unroll
            for (int h = 0; h < 2; ++h) {
                int r0 = w * 32 + h * 16;
                int row = r0 + (l >> 2);
                int slog = (l & 3) ^ ((row >> 1) & 3);
                const u16* g = gsrc[mat] + (size_t)row * DIMD + k0 + slog * 8;
                void* d = (char*)(&lds[0][0][0]) + mat * 8192 + r0 * 64;
                ld_g2l_16(g, d);
            }
        __syncthreads();

        short8 af[4], bf[4];
        #pragma unroll
        for (int m = 0; m < 4; ++m) {
            int rowa = wr * 64 + m * 16 + (l & 15);
            int pa = (l >> 4) ^ ((rowa >> 1) & 3);
            af[m] = *(const short8*)((const char*)lds + rowa * 64 + pa * 16);
            int rowb = wc * 64 + m * 16 + (l & 15);
            int pb = (l >> 4) ^ ((rowb >> 1) & 3);
            bf[m] = *(const short8*)((const char*)lds + 8192 + rowb * 64 + pb * 16);
        }

        #pragma unroll
        for (int m = 0; m < 4; ++m)
            #pragma unroll
            for (int n = 0; n < 4; ++n)
                acc[m][n] = __builtin_amdgcn_mfma_f32_16x16x32_bf16(af[m], bf[n], acc[m][n], 0, 0, 0);
        __syncthreads();
    }

    // fused epilogue: l2 -> t + t^2 + t^4 + t^8 + t^16
    float gamma = gamma_p[0];
    float sgn_r = (rowBase < b) ? 1.f : -1.f;
    float sgn_c = (colBase < b) ? 1.f : -1.f;
    float wgt = ((ti == tj) ? 1.f : 2.f) * sgn_r * sgn_c;

    float cs[4];
    #pragma unroll
    for (int n = 0; n < 4; ++n) cs[n] = sq[colBase + wc * 64 + n * 16 + (l & 15)];

    float psum = 0.f;
    #pragma unroll
    for (int m = 0; m < 4; ++m) {
        float rs[4];
        #pragma unroll
        for (int r = 0; r < 4; ++r)
            rs[r] = sq[rowBase + wr * 64 + m * 16 + (l >> 4) * 4 + r];
        #pragma unroll
        for (int n = 0; n < 4; ++n) {
            #pragma unroll
            for (int r = 0; r < 4; ++r) {
                float l2v = fmaxf(rs[r] + cs[n] - 2.f * acc[m][n][r], 0.f);
                float t1 = __expf(-l2v * gamma);
                float t2 = t1 * t1;
                float t4 = t2 * t2;
                float t8 = t4 * t4;
                float t16 = t8 * t8;
                psum += t1 + t2 + t4 + t8 + t16;
            }
        }
    }

    double v = (double)psum * (double)wgt;
    #pragma unroll
    for (int off = 32; off; off >>= 1) v += __shfl_down(v, off);
    __shared__ double wred[4];
    if (l == 0) wred[w] = v;
    __syncthreads();
    if (t == 0) atomicAdd(&slots[u & (NSLOTS - 1)], wred[0] + wred[1] + wred[2] + wred[3]);
}

__global__ void out_kernel(const double* __restrict__ slots,
                           float* __restrict__ out, int b) {
    int t = threadIdx.x;
    double v = slots[t];
    #pragma unroll
    for (int off = 32; off; off >>= 1) v += __shfl_down(v, off);
    if (t == 0) out[0] = (float)(v / ((double)b * (double)b));
}

extern "C" void kernel_launch(void* const* d_in, const int* in_sizes, int n_in,
                              void* d_out, int out_size, void* d_ws, size_t ws_size,
                              hipStream_t stream) {
    const float* src = (const float*)d_in[0];
    const float* tgt = (const float*)d_in[1];
    int b = in_sizes[0] / DIMD;   // 4096
    int n = 2 * b;                // 8192

    char* ws = (char*)d_ws;
    u16*    Hbuf   = (u16*)(ws + WS_H);
    float*  sqBuf  = (float*)(ws + WS_SQ);
    char*   red    = ws + WS_RED;
    float*  colsum = (float*)red;
    double* sumsq  = (double*)(red + 2048);
    double* slots  = (double*)(red + 2056);
    float*  gamma  = (float*)(red + 2568);

    hipMemsetAsync(red, 0, RED_BYTES, stream);

    prep_kernel<<<n / 64, 256, 0, stream>>>(src, tgt, Hbuf, sqBuf, colsum, sumsq, b);
    bw_kernel<<<1, 256, 0, stream>>>(colsum, sumsq, gamma, n);
    pair_kernel<<<NPAIRS, 256, 0, stream>>>(Hbuf, sqBuf, gamma, slots, b);
    out_kernel<<<1, 64, 0, stream>>>(slots, (float*)d_out, b);
}